// Round 7
// baseline (320.129 us; speedup 1.0000x reference)
//
#include <hip/hip_runtime.h>
#include <stdint.h>

typedef uint16_t u16;
typedef uint8_t  u8;
typedef __bf16 bf16x8 __attribute__((ext_vector_type(8)));
typedef float f32x4 __attribute__((ext_vector_type(4)));
typedef int i32x4 __attribute__((ext_vector_type(4)));
typedef int i32x8 __attribute__((ext_vector_type(8)));

#define NSC    8             // super-chunks (grid y)
#define NTILES 250           // 32000/128 n-tiles
#define NPART  32            // 8 sc x 4 col-quarter blocks
#define NROWS  4096          // 2L

__device__ __forceinline__ u16 f2b(float x) {
    uint32_t u = __float_as_uint(x);
    u += 0x7FFF + ((u >> 16) & 1);
    return (u16)(u >> 16);
}

// fp32 -> fp8 e4m3fn (OCP), RNE, clamp to +-448. Hand-rolled (no builtin risk).
__device__ __forceinline__ u8 f32_to_fp8(float x) {
    uint32_t sign = (__float_as_uint(x) >> 24) & 0x80;
    float ax = fminf(fabsf(x), 448.f);
    uint32_t r;
    if (ax < 0.015625f) {                      // subnormal: m * 2^-9
        r = (uint32_t)(int)rintf(ax * 512.f);  // rolls to 0x08 (=2^-6) at 8: still correct
    } else {
        uint32_t u = __float_as_uint(ax);
        u += 0x0007FFFF + ((u >> 20) & 1);     // RNE into 3-bit mantissa
        r = (((u >> 23) - 120) << 3) | ((u >> 20) & 7);
    }
    return (u8)(sign | r);
}

// fp8 e4m3fn -> fp32 (exact)
__device__ __forceinline__ float fp8_val(int b) {
    int e = (b >> 3) & 0xF, m = b & 7;
    float v = e ? __uint_as_float((uint32_t)(((e + 120) << 23) | (m << 20)))
                : (float)m * 0.001953125f;
    return (b & 0x80) ? -v : v;
}

// async global->LDS, 16B per lane. LDS side must be wave-uniform base + lane*16.
__device__ __forceinline__ void cp16(const void* g, void* l) {
    __builtin_amdgcn_global_load_lds(
        (const __attribute__((address_space(1))) uint32_t*)g,
        (__attribute__((address_space(3))) uint32_t*)l, 16, 0, 0);
}

__device__ __forceinline__ float fast_tanh(float x) {
    x = fminf(15.f, fmaxf(-15.f, x));
    float e = __expf(2.f * x);
    return (e - 1.f) / (e + 1.f);
}

// fused prep: blocks 0..255 convert Wc+Wp fp32->bf16; blocks 256..2303 span
// gathers -> bf16 ctx/phr; blocks 2304..4351 convert Wo fp32->fp8 (x32 scale)
__global__ void k_prep(const float* __restrict__ Wc, const float* __restrict__ Wp,
                       const float* __restrict__ hidden, const int* __restrict__ begins,
                       const int* __restrict__ ends, const int* __restrict__ bids,
                       const float* __restrict__ Wo, u8* __restrict__ Wo8,
                       u16* __restrict__ Wc_b, u16* __restrict__ Wp_b,
                       u16* __restrict__ ctx, u16* __restrict__ phr) {
    int b = blockIdx.x;
    if (b >= 2304) {   // Wo fp32 -> fp8, grid-stride over 16,384,000 elems
        int i = ((b - 2304) * 256 + threadIdx.x) * 4;
        const int stride = 2048 * 256 * 4;
        for (; i < 16384000; i += stride) {
            float4 v = *(const float4*)(Wo + i);
            u8 o[4] = {f32_to_fp8(v.x * 32.f), f32_to_fp8(v.y * 32.f),
                       f32_to_fp8(v.z * 32.f), f32_to_fp8(v.w * 32.f)};
            *(uint32_t*)(Wo8 + i) = *(const uint32_t*)o;
        }
        return;
    }
    if (b < 256) {
        int i = b * 2048 + threadIdx.x * 8;
        float4 a0 = *(const float4*)(Wc + i), a1 = *(const float4*)(Wc + i + 4);
        float4 p0 = *(const float4*)(Wp + i), p1 = *(const float4*)(Wp + i + 4);
        u16 oc[8] = {f2b(a0.x), f2b(a0.y), f2b(a0.z), f2b(a0.w),
                     f2b(a1.x), f2b(a1.y), f2b(a1.z), f2b(a1.w)};
        u16 op[8] = {f2b(p0.x), f2b(p0.y), f2b(p0.z), f2b(p0.w),
                     f2b(p1.x), f2b(p1.y), f2b(p1.z), f2b(p1.w)};
        *(int4*)(Wc_b + i) = *(const int4*)oc;
        *(int4*)(Wp_b + i) = *(const int4*)op;
        return;
    }
    int l = b - 256;
    int bg = begins[l], e = ends[l], bd = bids[l];
    const float* h_bm1 = hidden + ((size_t)(bg - 1) * 32 + bd) * 1024;
    const float* h_e   = hidden + ((size_t)e * 32 + bd) * 1024;
    const float* h_b   = hidden + ((size_t)bg * 32 + bd) * 1024;
    const float* h_em1 = hidden + ((size_t)(e - 1) * 32 + bd) * 1024;
    int d = threadIdx.x * 4;
    float4 c4 = (d < 512) ? *(const float4*)(h_bm1 + d) : *(const float4*)(h_e + d);
    float4 b4 = *(const float4*)(h_b + d);
    float4 e4 = *(const float4*)(h_em1 + d);
    u16 co[4] = {f2b(c4.x), f2b(c4.y), f2b(c4.z), f2b(c4.w)};
    u16 po[4] = {f2b(0.5f * (b4.x + e4.x)), f2b(0.5f * (b4.y + e4.y)),
                 f2b(0.5f * (b4.z + e4.z)), f2b(0.5f * (b4.w + e4.w))};
    *(uint64_t*)(ctx + (size_t)l * 1024 + d) = *(const uint64_t*)co;
    *(uint64_t*)(phr + (size_t)l * 1024 + d) = *(const uint64_t*)po;
}

// feats8[z*2048+m][n] = fp8(16 * tanh(A[m].W[n] + bias[n])), bf16 MFMA inputs
__global__ __launch_bounds__(256) void k_feats(const u16* __restrict__ ctx, const u16* __restrict__ phr,
        const u16* __restrict__ Wc, const u16* __restrict__ Wp,
        const float* __restrict__ bc, const float* __restrict__ bp,
        u8* __restrict__ feats) {
    __shared__ __align__(16) u16 lA[64 * 32];
    __shared__ __align__(16) u16 lB[64 * 32];
    int z = blockIdx.z;
    const u16* A = z ? phr : ctx;
    const u16* W = z ? Wp : Wc;
    const float* bias = z ? bp : bc;
    int m0 = blockIdx.x * 64;
    int n0 = blockIdx.y * 64;
    int t = threadIdx.x;
    int lane = t & 63, w = t >> 6;
    int lrow = lane & 15, lq = lane >> 4;
    f32x4 zero = {0.f, 0.f, 0.f, 0.f};
    f32x4 acc[4];
    for (int i = 0; i < 4; i++) acc[i] = zero;
    int row = t >> 2, kseg = (t & 3) * 8;
    for (int kt = 0; kt < 32; kt++) {
        int k0 = kt * 32;
        __syncthreads();
        cp16(&A[(size_t)(m0 + row) * 1024 + k0 + kseg], &lA[t * 8]);
        cp16(&W[(size_t)(n0 + row) * 1024 + k0 + kseg], &lB[t * 8]);
        __syncthreads();
        bf16x8 af = *(bf16x8*)&lA[(w * 16 + lrow) * 32 + lq * 8];
        for (int ns = 0; ns < 4; ns++) {
            bf16x8 bfr = *(bf16x8*)&lB[(ns * 16 + lrow) * 32 + lq * 8];
            acc[ns] = __builtin_amdgcn_mfma_f32_16x16x32_bf16(af, bfr, acc[ns], 0, 0, 0);
        }
    }
    int zbase = z * 2048;
    for (int ns = 0; ns < 4; ns++) {
        int col = n0 + ns * 16 + lrow;
        float bv = bias[col];
        for (int r = 0; r < 4; r++) {
            int orow = zbase + m0 + w * 16 + lq * 4 + r;
            feats[(size_t)orow * 512 + col] = f32_to_fp8(16.f * fast_tanh(acc[ns][r] + bv));
        }
    }
}

// big GEMM + row sum-of-exp, MX-fp8: feats8[4096][512] @ Wo8[32000][512]^T.
//
// v7 = v5 inner math, de-lockstepped: grid (32, 8, 4) = 1024 blocks of 128
// threads (2 waves) -> 4 INDEPENDENT blocks/CU. v5's single 512-thread block
// barrier-synced all 8 waves 4x/tile, so every stage-wait stalled the whole
// CU (MfmaUtil 27.6 + VALUBusy 27.7 = ~45% idle). The 4 col-quarter wave
// pairs read DISJOINT 32-row slices of B, so the 8-wave barrier coupled
// waves sharing nothing. Now each block stages only its own 4 KB quarter
// chunk (ring = 4 x 4 KB = 16 KB LDS; 4 blocks/CU = same 64 KB, same global
// traffic, same cp16 count/wave, same vmcnt 4/2/0 discipline, same swizzle
// on quarter-local rows) with a 2-wave barrier; blocks slide independently
// so one block's MFMA fills another's stage-wait.
// Wave = 64 rows x 32 cols (mi=4, ni=2), af[4][4] = 128 regs in the unified
// file (~244/wave total, v5-measured) -> 8 waves/CU, no spill @ (128,1).
// exp folded to exp2 domain (v_exp IS 2^x): exp(acc/512+bv) =
// exp2(fma(acc, log2e/512, bv*log2e)) -- pure instruction save vs __expf.
// No max-tracking: |logit| <= 22.6, exp never overflows fp32.
__global__ __launch_bounds__(128, 1) void k_lse(const u8* __restrict__ feats,
        const u8* __restrict__ Wo, const float* __restrict__ bo, float* __restrict__ ps) {
    __shared__ __align__(16) u8 lds[4][32 * 128];    // quarter B ring = 16 KB
    int m0 = blockIdx.x * 128;
    int sc = blockIdx.y;
    int q  = blockIdx.z;                             // col-quarter 0..3
    int ts = (NTILES * sc) / NSC, te = (NTILES * (sc + 1)) / NSC;
    int t = threadIdx.x;                             // 0..127
    int lane = t & 63, w = t >> 6;                   // w = 0..1: row-half
    int lrow = lane & 15, lq = lane >> 4;
    int wrow = w * 64;
    int xm = lrow & 7;                 // swizzle key (row&7 == lrow&7 for our rows)
    int xoA = ((2 * lq) ^ xm) * 16;    // swizzled 16B slots for source k-chunks 2lq, 2lq+1
    int xoB = ((2 * lq + 1) ^ xm) * 16;

    // staging: 256 16B chunks per slot (32 rows x 8 slots), 2 per thread
    // (c = t and c = t+128; +128 -> row+16, same slot/XOR since 16%8==0).
    // chunk c -> row c>>3, phys slot c&7; src k-chunk = (c&7)^((c>>3)&7).
    int srow = t >> 3;
    int kb = ((t & 7) ^ ((t >> 3) & 7)) * 16;

    auto stageB = [&](int slot, int gr) {
        const u8* pB = Wo + (size_t)((gr >> 2) * 128 + q * 32 + srow) * 512
                     + (gr & 3) * 128 + kb;
        cp16(pB, &lds[slot][t * 16]);
        cp16(pB + (size_t)16 * 512, &lds[slot][t * 16 + 2048]);
    };

    int gr0 = ts * 4;                  // gr0 % 4 == 0 -> slot = gr & 3
    stageB(0, gr0);
    stageB(1, gr0 + 1);
    stageB(2, gr0 + 2);

    // ---- A tile -> registers (once per block); rows m0+wrow+mi*16+lrow ----
    i32x8 af[4][4];
#pragma unroll
    for (int mi = 0; mi < 4; mi++) {
        const u8* pa = feats + (size_t)(m0 + wrow + mi * 16 + lrow) * 512 + lq * 32;
#pragma unroll
        for (int kc = 0; kc < 4; kc++) {
            i32x4 lo = *(const i32x4*)(pa + kc * 128);
            i32x4 hi = *(const i32x4*)(pa + kc * 128 + 16);
            af[mi][kc] = __builtin_shufflevector(lo, hi, 0, 1, 2, 3, 4, 5, 6, 7);
        }
    }

    const float C1 = 0.0028177637517362567f;        // log2(e)/512
    const float L2E = 1.4426950408889634f;
    float s_state[4][4];
    for (int mi = 0; mi < 4; mi++)
        for (int r = 0; r < 4; r++) s_state[mi][r] = 0.f;
    f32x4 zero = {0.f, 0.f, 0.f, 0.f};
    f32x4 acc[4][2];

    for (int tile = ts; tile < te; ++tile) {
        int grt = tile * 4;
        bool notlast = (tile + 1 < te);
#pragma unroll
        for (int mi = 0; mi < 4; mi++)
#pragma unroll
            for (int ni = 0; ni < 2; ni++) acc[mi][ni] = zero;
#pragma unroll
        for (int kc = 0; kc < 4; kc++) {
            // slot kc ready once all but the 2 newer stages (2 cp16 each) retired
            if (notlast || kc < 2)
                asm volatile("s_waitcnt vmcnt(4)" ::: "memory");
            else if (kc == 2)
                asm volatile("s_waitcnt vmcnt(2)" ::: "memory");
            else
                asm volatile("s_waitcnt vmcnt(0)" ::: "memory");
            __builtin_amdgcn_s_barrier();
            if (notlast || kc == 0)
                stageB((kc + 3) & 3, grt + kc + 3);   // prefetch depth 3
            const u8* bufB = lds[kc];
            __builtin_amdgcn_s_setprio(1);
#pragma unroll
            for (int ni = 0; ni < 2; ni++) {
                const u8* pb = bufB + (ni * 16 + lrow) * 128;
                i32x4 blo = *(const i32x4*)(pb + xoA);
                i32x4 bhi = *(const i32x4*)(pb + xoB);
                i32x8 bfr = __builtin_shufflevector(blo, bhi, 0, 1, 2, 3, 4, 5, 6, 7);
#pragma unroll
                for (int mi = 0; mi < 4; mi++)
                    acc[mi][ni] = __builtin_amdgcn_mfma_scale_f32_16x16x128_f8f6f4(
                        af[mi][kc], bfr, acc[mi][ni], 0, 0,
                        0, 0x7F7F7F7F, 0, 0x7F7F7F7F);
            }
            __builtin_amdgcn_s_setprio(0);
        }
        // epilogue for this n-tile: exp accumulate (overlaps in-flight stages)
        int n0 = tile * 128 + q * 32;
#pragma unroll
        for (int ni = 0; ni < 2; ni++) {
            float bvl = bo[n0 + ni * 16 + lrow] * L2E;
#pragma unroll
            for (int mi = 0; mi < 4; mi++)
#pragma unroll
                for (int r = 0; r < 4; r++)
                    s_state[mi][r] += exp2f(fmaf(acc[mi][ni][r], C1, bvl));
        }
    }
    // merge cols across the 16 lanes of each quad-group (xor 1,2,4,8 stays in-group)
    for (int mi = 0; mi < 4; mi++)
    for (int r = 0; r < 4; r++) {
        float s = s_state[mi][r];
        for (int off = 1; off < 16; off <<= 1) s += __shfl_xor(s, off);
        if (lrow == 0) {
            int row = m0 + wrow + mi * 16 + lq * 4 + r;
            ps[row * NPART + sc * 4 + q] = s;
        }
    }
}

// tag logits from fp8: one wave per row does BOTH tags; logit = dot/512 + bo
__global__ void k_taglog(const u8* __restrict__ feats, const u8* __restrict__ Wo,
        const float* __restrict__ bo, const int* __restrict__ tags, float* __restrict__ tlog) {
    int i = blockIdx.x * 4 + (threadIdx.x >> 6);   // row 0..4095
    int lane = threadIdx.x & 63;
    int t0 = tags[(i & 2047) * 2 + 0];
    int t1 = tags[(i & 2047) * 2 + 1];
    uint64_t fa = *(const uint64_t*)(feats + (size_t)i * 512 + lane * 8);
    uint64_t wa = *(const uint64_t*)(Wo + (size_t)t0 * 512 + lane * 8);
    uint64_t wb = *(const uint64_t*)(Wo + (size_t)t1 * 512 + lane * 8);
    float s0 = 0.f, s1 = 0.f;
    for (int j = 0; j < 8; j++) {
        float fv = fp8_val((int)((fa >> (8 * j)) & 0xFF));
        s0 += fv * fp8_val((int)((wa >> (8 * j)) & 0xFF));
        s1 += fv * fp8_val((int)((wb >> (8 * j)) & 0xFF));
    }
    for (int off = 32; off >= 1; off >>= 1) {
        s0 += __shfl_down(s0, off);
        s1 += __shfl_down(s1, off);
    }
    if (lane == 0) {
        tlog[i * 2 + 0] = s0 * (1.f / 512.f) + bo[t0];
        tlog[i * 2 + 1] = s1 * (1.f / 512.f) + bo[t1];
    }
}

// lse = log(sum of chunk partials) + loss; 16 blocks x 256 rows, atomicAdd
__global__ void k_final(const float* __restrict__ ps,
        const float* __restrict__ tlog, const int* __restrict__ tags,
        const float* __restrict__ dp, float* __restrict__ out) {
    __shared__ float red[256];
    int i = blockIdx.x * 256 + threadIdx.x;
    float S = 0.f;
    for (int j = 0; j < NPART; j++) S += ps[i * NPART + j];
    float lse = logf(S);
    float num = 0.f, den = 0.f;
    for (int k = 0; k < 2; k++) {
        int tg = tags[(i & 2047) * 2 + k];
        float r = 1.0f - dp[tg];
        num += r * (lse - tlog[i * 2 + k]);
        den += r;
    }
    red[threadIdx.x] = num / den;
    __syncthreads();
    for (int s = 128; s > 0; s >>= 1) {
        if (threadIdx.x < s) red[threadIdx.x] += red[threadIdx.x + s];
        __syncthreads();
    }
    if (threadIdx.x == 0) atomicAdd(out, red[0] / (4096.0f + 1e-5f));
}

extern "C" void kernel_launch(void* const* d_in, const int* in_sizes, int n_in,
                              void* d_out, int out_size, void* d_ws, size_t ws_size,
                              hipStream_t stream) {
    const float* hidden = (const float*)d_in[0];
    const float* Wc     = (const float*)d_in[1];
    const float* bc     = (const float*)d_in[2];
    const float* Wp     = (const float*)d_in[3];
    const float* bp     = (const float*)d_in[4];
    const float* Wo     = (const float*)d_in[5];
    const float* bo     = (const float*)d_in[6];
    const float* dp     = (const float*)d_in[7];
    const int* begins   = (const int*)d_in[8];
    const int* ends     = (const int*)d_in[9];
    const int* bids     = (const int*)d_in[10];
    const int* tags     = (const int*)d_in[11];
    float* out = (float*)d_out;

    // workspace carve (all 16B-aligned)
    u8*  Wo8     = (u8*)d_ws;                          // 16,384,000 B (fp8 x32)
    u16* Wc_b    = (u16*)((char*)d_ws + 16384000);     // 512*1024 bf16
    u16* Wp_b    = Wc_b + 524288;
    u16* ctx_b   = Wp_b + 524288;                      // 2048*1024 bf16
    u16* phr_b   = ctx_b + 2097152;
    u8*  feats8  = (u8*)(phr_b + 2097152);             // 4096*512 fp8 x16
    // ps/tlog alias the ctx region (dead after k_feats; in-stream order safe)
    float* ps    = (float*)ctx_b;                      // 4096*32*4 = 512 KB
    float* tlog  = ps + NROWS * NPART;                 // 8192

    k_prep<<<4352, 256, 0, stream>>>(Wc, Wp, hidden, begins, ends, bids,
                                     Wo, Wo8, Wc_b, Wp_b, ctx_b, phr_b);
    k_feats<<<dim3(32, 8, 2), 256, 0, stream>>>(ctx_b, phr_b, Wc_b, Wp_b, bc, bp, feats8);
    k_lse<<<dim3(32, NSC, 4), 128, 0, stream>>>(feats8, Wo8, bo, ps);
    k_taglog<<<1024, 256, 0, stream>>>(feats8, Wo8, bo, tags, tlog);
    hipMemsetAsync(d_out, 0, sizeof(float), stream);
    k_final<<<16, 256, 0, stream>>>(ps, tlog, tags, dp, out);
}

// Round 8
// 272.366 us; speedup vs baseline: 1.1754x; 1.1754x over previous
//
#include <hip/hip_runtime.h>
#include <stdint.h>

typedef uint16_t u16;
typedef uint8_t  u8;
typedef __bf16 bf16x8 __attribute__((ext_vector_type(8)));
typedef float f32x4 __attribute__((ext_vector_type(4)));
typedef int i32x4 __attribute__((ext_vector_type(4)));
typedef int i32x8 __attribute__((ext_vector_type(8)));

#define NSC    8             // super-chunks (grid y)
#define NTILES 250           // 32000/128 n-tiles
#define NPART  32            // 8 sc x 4 col-quarter blocks
#define NROWS  4096          // 2L

__device__ __forceinline__ u16 f2b(float x) {
    uint32_t u = __float_as_uint(x);
    u += 0x7FFF + ((u >> 16) & 1);
    return (u16)(u >> 16);
}

// fp32 -> fp8 e4m3fn (OCP), RNE, clamp to +-448. Hand-rolled (no builtin risk).
__device__ __forceinline__ u8 f32_to_fp8(float x) {
    uint32_t sign = (__float_as_uint(x) >> 24) & 0x80;
    float ax = fminf(fabsf(x), 448.f);
    uint32_t r;
    if (ax < 0.015625f) {                      // subnormal: m * 2^-9
        r = (uint32_t)(int)rintf(ax * 512.f);  // rolls to 0x08 (=2^-6) at 8: still correct
    } else {
        uint32_t u = __float_as_uint(ax);
        u += 0x0007FFFF + ((u >> 20) & 1);     // RNE into 3-bit mantissa
        r = (((u >> 23) - 120) << 3) | ((u >> 20) & 7);
    }
    return (u8)(sign | r);
}

// fp8 e4m3fn -> fp32 (exact)
__device__ __forceinline__ float fp8_val(int b) {
    int e = (b >> 3) & 0xF, m = b & 7;
    float v = e ? __uint_as_float((uint32_t)(((e + 120) << 23) | (m << 20)))
                : (float)m * 0.001953125f;
    return (b & 0x80) ? -v : v;
}

// async global->LDS, 16B per lane. LDS side must be wave-uniform base + lane*16.
__device__ __forceinline__ void cp16(const void* g, void* l) {
    __builtin_amdgcn_global_load_lds(
        (const __attribute__((address_space(1))) uint32_t*)g,
        (__attribute__((address_space(3))) uint32_t*)l, 16, 0, 0);
}

__device__ __forceinline__ float fast_tanh(float x) {
    x = fminf(15.f, fmaxf(-15.f, x));
    float e = __expf(2.f * x);
    return (e - 1.f) / (e + 1.f);
}

// fused prep: blocks 0..255 convert Wc+Wp fp32->bf16; blocks 256..2303 span
// gathers -> bf16 ctx/phr; blocks 2304..4351 convert Wo fp32->fp8 (x32 scale)
__global__ void k_prep(const float* __restrict__ Wc, const float* __restrict__ Wp,
                       const float* __restrict__ hidden, const int* __restrict__ begins,
                       const int* __restrict__ ends, const int* __restrict__ bids,
                       const float* __restrict__ Wo, u8* __restrict__ Wo8,
                       u16* __restrict__ Wc_b, u16* __restrict__ Wp_b,
                       u16* __restrict__ ctx, u16* __restrict__ phr) {
    int b = blockIdx.x;
    if (b >= 2304) {   // Wo fp32 -> fp8, grid-stride over 16,384,000 elems
        int i = ((b - 2304) * 256 + threadIdx.x) * 4;
        const int stride = 2048 * 256 * 4;
        for (; i < 16384000; i += stride) {
            float4 v = *(const float4*)(Wo + i);
            u8 o[4] = {f32_to_fp8(v.x * 32.f), f32_to_fp8(v.y * 32.f),
                       f32_to_fp8(v.z * 32.f), f32_to_fp8(v.w * 32.f)};
            *(uint32_t*)(Wo8 + i) = *(const uint32_t*)o;
        }
        return;
    }
    if (b < 256) {
        int i = b * 2048 + threadIdx.x * 8;
        float4 a0 = *(const float4*)(Wc + i), a1 = *(const float4*)(Wc + i + 4);
        float4 p0 = *(const float4*)(Wp + i), p1 = *(const float4*)(Wp + i + 4);
        u16 oc[8] = {f2b(a0.x), f2b(a0.y), f2b(a0.z), f2b(a0.w),
                     f2b(a1.x), f2b(a1.y), f2b(a1.z), f2b(a1.w)};
        u16 op[8] = {f2b(p0.x), f2b(p0.y), f2b(p0.z), f2b(p0.w),
                     f2b(p1.x), f2b(p1.y), f2b(p1.z), f2b(p1.w)};
        *(int4*)(Wc_b + i) = *(const int4*)oc;
        *(int4*)(Wp_b + i) = *(const int4*)op;
        return;
    }
    int l = b - 256;
    int bg = begins[l], e = ends[l], bd = bids[l];
    const float* h_bm1 = hidden + ((size_t)(bg - 1) * 32 + bd) * 1024;
    const float* h_e   = hidden + ((size_t)e * 32 + bd) * 1024;
    const float* h_b   = hidden + ((size_t)bg * 32 + bd) * 1024;
    const float* h_em1 = hidden + ((size_t)(e - 1) * 32 + bd) * 1024;
    int d = threadIdx.x * 4;
    float4 c4 = (d < 512) ? *(const float4*)(h_bm1 + d) : *(const float4*)(h_e + d);
    float4 b4 = *(const float4*)(h_b + d);
    float4 e4 = *(const float4*)(h_em1 + d);
    u16 co[4] = {f2b(c4.x), f2b(c4.y), f2b(c4.z), f2b(c4.w)};
    u16 po[4] = {f2b(0.5f * (b4.x + e4.x)), f2b(0.5f * (b4.y + e4.y)),
                 f2b(0.5f * (b4.z + e4.z)), f2b(0.5f * (b4.w + e4.w))};
    *(uint64_t*)(ctx + (size_t)l * 1024 + d) = *(const uint64_t*)co;
    *(uint64_t*)(phr + (size_t)l * 1024 + d) = *(const uint64_t*)po;
}

// feats8[z*2048+m][n] = fp8(16 * tanh(A[m].W[n] + bias[n])), bf16 MFMA inputs
__global__ __launch_bounds__(256) void k_feats(const u16* __restrict__ ctx, const u16* __restrict__ phr,
        const u16* __restrict__ Wc, const u16* __restrict__ Wp,
        const float* __restrict__ bc, const float* __restrict__ bp,
        u8* __restrict__ feats) {
    __shared__ __align__(16) u16 lA[64 * 32];
    __shared__ __align__(16) u16 lB[64 * 32];
    int z = blockIdx.z;
    const u16* A = z ? phr : ctx;
    const u16* W = z ? Wp : Wc;
    const float* bias = z ? bp : bc;
    int m0 = blockIdx.x * 64;
    int n0 = blockIdx.y * 64;
    int t = threadIdx.x;
    int lane = t & 63, w = t >> 6;
    int lrow = lane & 15, lq = lane >> 4;
    f32x4 zero = {0.f, 0.f, 0.f, 0.f};
    f32x4 acc[4];
    for (int i = 0; i < 4; i++) acc[i] = zero;
    int row = t >> 2, kseg = (t & 3) * 8;
    for (int kt = 0; kt < 32; kt++) {
        int k0 = kt * 32;
        __syncthreads();
        cp16(&A[(size_t)(m0 + row) * 1024 + k0 + kseg], &lA[t * 8]);
        cp16(&W[(size_t)(n0 + row) * 1024 + k0 + kseg], &lB[t * 8]);
        __syncthreads();
        bf16x8 af = *(bf16x8*)&lA[(w * 16 + lrow) * 32 + lq * 8];
        for (int ns = 0; ns < 4; ns++) {
            bf16x8 bfr = *(bf16x8*)&lB[(ns * 16 + lrow) * 32 + lq * 8];
            acc[ns] = __builtin_amdgcn_mfma_f32_16x16x32_bf16(af, bfr, acc[ns], 0, 0, 0);
        }
    }
    int zbase = z * 2048;
    for (int ns = 0; ns < 4; ns++) {
        int col = n0 + ns * 16 + lrow;
        float bv = bias[col];
        for (int r = 0; r < 4; r++) {
            int orow = zbase + m0 + w * 16 + lq * 4 + r;
            feats[(size_t)orow * 512 + col] = f32_to_fp8(16.f * fast_tanh(acc[ns][r] + bv));
        }
    }
}

// big GEMM + row sum-of-exp, MX-fp8: feats8[4096][512] @ Wo8[32000][512]^T.
//
// v8 = v7 (independent 2-wave blocks, grid (32,8,4) = 4 blocks/CU) with the
// occupancy FIXED. v7 shipped 132 arch + 128 AGPR = 260 unified regs/wave,
// one over the 256 boundary -> 1 wave/SIMD -> 4 waves/CU (Occ 11%) -> 144us.
// Yet per-wave issue rate IMPROVED 1.34x vs v5's 8-wave lockstep -- the
// de-lockstep mechanism works; it just lost half its waves. Fix:
// __launch_bounds__(128, 2) caps the wave at 256 unified (v5 proved ~244
// achievable for near-identical code) + manual trims: xoB == xoA ^ 16
// (since (2lq+1)^xm = ((2lq)^xm)^1), precomputed pBbase/bop pointers.
// -> 2 waves/SIMD, 8 waves/CU across 4 INDEPENDENT barrier groups.
// Everything else identical to v7 (absmax-0 proven): 4-slot quarter ring
// (4x4KB LDS), depth-3 prefetch, counted vmcnt 4/2/0, one s_barrier per kc,
// setprio(1) around MFMA, 16B-slot XOR swizzle, exp2-domain epilogue.
// No max-tracking: |logit| <= 22.6, exp never overflows fp32.
__global__ __launch_bounds__(128, 2) void k_lse(const u8* __restrict__ feats,
        const u8* __restrict__ Wo, const float* __restrict__ bo, float* __restrict__ ps) {
    __shared__ __align__(16) u8 lds[4][32 * 128];    // quarter B ring = 16 KB
    int m0 = blockIdx.x * 128;
    int sc = blockIdx.y;
    int q  = blockIdx.z;                             // col-quarter 0..3
    int ts = (NTILES * sc) / NSC, te = (NTILES * (sc + 1)) / NSC;
    int t = threadIdx.x;                             // 0..127
    int lane = t & 63, w = t >> 6;                   // w = 0..1: row-half
    int lrow = lane & 15, lq = lane >> 4;
    int wrow = w * 64;
    int xm = lrow & 7;                 // swizzle key (row&7 == lrow&7 for our rows)
    int xoA = ((2 * lq) ^ xm) * 16;    // swizzled 16B slot, k-chunk 2lq; 2lq+1 is xoA^16

    // staging: 256 16B chunks per slot (32 rows x 8 slots), 2 per thread
    // (c = t and c = t+128; +128 -> row+16, same slot/XOR since 16%8==0).
    // chunk c -> row c>>3, phys slot c&7; src k-chunk = (c&7)^((c>>3)&7).
    const u8* pBbase = Wo + (size_t)(q * 32 + (t >> 3)) * 512
                     + ((t & 7) ^ ((t >> 3) & 7)) * 16;

    auto stageB = [&](int slot, int gr) {
        const u8* pB = pBbase + (size_t)(gr >> 2) * 65536 + (gr & 3) * 128;
        cp16(pB, &lds[slot][t * 16]);
        cp16(pB + (size_t)16 * 512, &lds[slot][t * 16 + 2048]);
    };

    int gr0 = ts * 4;                  // gr0 % 4 == 0 -> slot = gr & 3
    stageB(0, gr0);
    stageB(1, gr0 + 1);
    stageB(2, gr0 + 2);

    // ---- A tile -> registers (once per block); rows m0+wrow+mi*16+lrow ----
    i32x8 af[4][4];
#pragma unroll
    for (int mi = 0; mi < 4; mi++) {
        const u8* pa = feats + (size_t)(m0 + wrow + mi * 16 + lrow) * 512 + lq * 32;
#pragma unroll
        for (int kc = 0; kc < 4; kc++) {
            i32x4 lo = *(const i32x4*)(pa + kc * 128);
            i32x4 hi = *(const i32x4*)(pa + kc * 128 + 16);
            af[mi][kc] = __builtin_shufflevector(lo, hi, 0, 1, 2, 3, 4, 5, 6, 7);
        }
    }

    const float C1 = 0.0028177637517362567f;        // log2(e)/512
    const float L2E = 1.4426950408889634f;
    const float* bop = bo + q * 32 + lrow;          // epilogue bias base
    float s_state[4][4];
    for (int mi = 0; mi < 4; mi++)
        for (int r = 0; r < 4; r++) s_state[mi][r] = 0.f;
    f32x4 zero = {0.f, 0.f, 0.f, 0.f};
    f32x4 acc[4][2];

    for (int tile = ts; tile < te; ++tile) {
        int grt = tile * 4;
        bool notlast = (tile + 1 < te);
#pragma unroll
        for (int mi = 0; mi < 4; mi++)
#pragma unroll
            for (int ni = 0; ni < 2; ni++) acc[mi][ni] = zero;
#pragma unroll
        for (int kc = 0; kc < 4; kc++) {
            // slot kc ready once all but the 2 newer stages (2 cp16 each) retired
            if (notlast || kc < 2)
                asm volatile("s_waitcnt vmcnt(4)" ::: "memory");
            else if (kc == 2)
                asm volatile("s_waitcnt vmcnt(2)" ::: "memory");
            else
                asm volatile("s_waitcnt vmcnt(0)" ::: "memory");
            __builtin_amdgcn_s_barrier();
            if (notlast || kc == 0)
                stageB((kc + 3) & 3, grt + kc + 3);   // prefetch depth 3
            const u8* bufB = lds[kc];
            __builtin_amdgcn_s_setprio(1);
#pragma unroll
            for (int ni = 0; ni < 2; ni++) {
                const u8* pb = bufB + (ni * 16 + lrow) * 128 + xoA;
                i32x4 blo = *(const i32x4*)(pb);
                i32x4 bhi = *(const i32x4*)((const u8*)((uintptr_t)pb ^ 16));
                i32x8 bfr = __builtin_shufflevector(blo, bhi, 0, 1, 2, 3, 4, 5, 6, 7);
#pragma unroll
                for (int mi = 0; mi < 4; mi++)
                    acc[mi][ni] = __builtin_amdgcn_mfma_scale_f32_16x16x128_f8f6f4(
                        af[mi][kc], bfr, acc[mi][ni], 0, 0,
                        0, 0x7F7F7F7F, 0, 0x7F7F7F7F);
            }
            __builtin_amdgcn_s_setprio(0);
        }
        // epilogue for this n-tile: exp accumulate (overlaps in-flight stages)
#pragma unroll
        for (int ni = 0; ni < 2; ni++) {
            float bvl = bop[tile * 128 + ni * 16] * L2E;
#pragma unroll
            for (int mi = 0; mi < 4; mi++)
#pragma unroll
                for (int r = 0; r < 4; r++)
                    s_state[mi][r] += exp2f(fmaf(acc[mi][ni][r], C1, bvl));
        }
    }
    // merge cols across the 16 lanes of each quad-group (xor 1,2,4,8 stays in-group)
    for (int mi = 0; mi < 4; mi++)
    for (int r = 0; r < 4; r++) {
        float s = s_state[mi][r];
        for (int off = 1; off < 16; off <<= 1) s += __shfl_xor(s, off);
        if (lrow == 0) {
            int row = m0 + wrow + mi * 16 + lq * 4 + r;
            ps[row * NPART + sc * 4 + q] = s;
        }
    }
}

// tag logits from fp8: one wave per row does BOTH tags; logit = dot/512 + bo
__global__ void k_taglog(const u8* __restrict__ feats, const u8* __restrict__ Wo,
        const float* __restrict__ bo, const int* __restrict__ tags, float* __restrict__ tlog) {
    int i = blockIdx.x * 4 + (threadIdx.x >> 6);   // row 0..4095
    int lane = threadIdx.x & 63;
    int t0 = tags[(i & 2047) * 2 + 0];
    int t1 = tags[(i & 2047) * 2 + 1];
    uint64_t fa = *(const uint64_t*)(feats + (size_t)i * 512 + lane * 8);
    uint64_t wa = *(const uint64_t*)(Wo + (size_t)t0 * 512 + lane * 8);
    uint64_t wb = *(const uint64_t*)(Wo + (size_t)t1 * 512 + lane * 8);
    float s0 = 0.f, s1 = 0.f;
    for (int j = 0; j < 8; j++) {
        float fv = fp8_val((int)((fa >> (8 * j)) & 0xFF));
        s0 += fv * fp8_val((int)((wa >> (8 * j)) & 0xFF));
        s1 += fv * fp8_val((int)((wb >> (8 * j)) & 0xFF));
    }
    for (int off = 32; off >= 1; off >>= 1) {
        s0 += __shfl_down(s0, off);
        s1 += __shfl_down(s1, off);
    }
    if (lane == 0) {
        tlog[i * 2 + 0] = s0 * (1.f / 512.f) + bo[t0];
        tlog[i * 2 + 1] = s1 * (1.f / 512.f) + bo[t1];
    }
}

// lse = log(sum of chunk partials) + loss; 16 blocks x 256 rows, atomicAdd
__global__ void k_final(const float* __restrict__ ps,
        const float* __restrict__ tlog, const int* __restrict__ tags,
        const float* __restrict__ dp, float* __restrict__ out) {
    __shared__ float red[256];
    int i = blockIdx.x * 256 + threadIdx.x;
    float S = 0.f;
    for (int j = 0; j < NPART; j++) S += ps[i * NPART + j];
    float lse = logf(S);
    float num = 0.f, den = 0.f;
    for (int k = 0; k < 2; k++) {
        int tg = tags[(i & 2047) * 2 + k];
        float r = 1.0f - dp[tg];
        num += r * (lse - tlog[i * 2 + k]);
        den += r;
    }
    red[threadIdx.x] = num / den;
    __syncthreads();
    for (int s = 128; s > 0; s >>= 1) {
        if (threadIdx.x < s) red[threadIdx.x] += red[threadIdx.x + s];
        __syncthreads();
    }
    if (threadIdx.x == 0) atomicAdd(out, red[0] / (4096.0f + 1e-5f));
}

extern "C" void kernel_launch(void* const* d_in, const int* in_sizes, int n_in,
                              void* d_out, int out_size, void* d_ws, size_t ws_size,
                              hipStream_t stream) {
    const float* hidden = (const float*)d_in[0];
    const float* Wc     = (const float*)d_in[1];
    const float* bc     = (const float*)d_in[2];
    const float* Wp     = (const float*)d_in[3];
    const float* bp     = (const float*)d_in[4];
    const float* Wo     = (const float*)d_in[5];
    const float* bo     = (const float*)d_in[6];
    const float* dp     = (const float*)d_in[7];
    const int* begins   = (const int*)d_in[8];
    const int* ends     = (const int*)d_in[9];
    const int* bids     = (const int*)d_in[10];
    const int* tags     = (const int*)d_in[11];
    float* out = (float*)d_out;

    // workspace carve (all 16B-aligned)
    u8*  Wo8     = (u8*)d_ws;                          // 16,384,000 B (fp8 x32)
    u16* Wc_b    = (u16*)((char*)d_ws + 16384000);     // 512*1024 bf16
    u16* Wp_b    = Wc_b + 524288;
    u16* ctx_b   = Wp_b + 524288;                      // 2048*1024 bf16
    u16* phr_b   = ctx_b + 2097152;
    u8*  feats8  = (u8*)(phr_b + 2097152);             // 4096*512 fp8 x16
    // ps/tlog alias the ctx region (dead after k_feats; in-stream order safe)
    float* ps    = (float*)ctx_b;                      // 4096*32*4 = 512 KB
    float* tlog  = ps + NROWS * NPART;                 // 8192

    k_prep<<<4352, 256, 0, stream>>>(Wc, Wp, hidden, begins, ends, bids,
                                     Wo, Wo8, Wc_b, Wp_b, ctx_b, phr_b);
    k_feats<<<dim3(32, 8, 2), 256, 0, stream>>>(ctx_b, phr_b, Wc_b, Wp_b, bc, bp, feats8);
    k_lse<<<dim3(32, NSC, 4), 128, 0, stream>>>(feats8, Wo8, bo, ps);
    k_taglog<<<1024, 256, 0, stream>>>(feats8, Wo8, bo, tags, tlog);
    hipMemsetAsync(d_out, 0, sizeof(float), stream);
    k_final<<<16, 256, 0, stream>>>(ps, tlog, tags, dp, out);
}

// Round 9
// 257.958 us; speedup vs baseline: 1.2410x; 1.0559x over previous
//
#include <hip/hip_runtime.h>
#include <stdint.h>

typedef uint16_t u16;
typedef uint8_t  u8;
typedef __bf16 bf16x8 __attribute__((ext_vector_type(8)));
typedef float f32x4 __attribute__((ext_vector_type(4)));
typedef int i32x4 __attribute__((ext_vector_type(4)));
typedef int i32x8 __attribute__((ext_vector_type(8)));

#define NSC    8             // super-chunks (grid y)
#define NTILES 250           // 32000/128 n-tiles
#define NPART  32            // 8 sc x 4 col-quarter blocks
#define NROWS  4096          // 2L

__device__ __forceinline__ u16 f2b(float x) {
    uint32_t u = __float_as_uint(x);
    u += 0x7FFF + ((u >> 16) & 1);
    return (u16)(u >> 16);
}

// fp32 -> fp8 e4m3fn (OCP), RNE, clamp to +-448. Hand-rolled (no builtin risk).
__device__ __forceinline__ u8 f32_to_fp8(float x) {
    uint32_t sign = (__float_as_uint(x) >> 24) & 0x80;
    float ax = fminf(fabsf(x), 448.f);
    uint32_t r;
    if (ax < 0.015625f) {                      // subnormal: m * 2^-9
        r = (uint32_t)(int)rintf(ax * 512.f);  // rolls to 0x08 (=2^-6) at 8: still correct
    } else {
        uint32_t u = __float_as_uint(ax);
        u += 0x0007FFFF + ((u >> 20) & 1);     // RNE into 3-bit mantissa
        r = (((u >> 23) - 120) << 3) | ((u >> 20) & 7);
    }
    return (u8)(sign | r);
}

// fp8 e4m3fn -> fp32 (exact)
__device__ __forceinline__ float fp8_val(int b) {
    int e = (b >> 3) & 0xF, m = b & 7;
    float v = e ? __uint_as_float((uint32_t)(((e + 120) << 23) | (m << 20)))
                : (float)m * 0.001953125f;
    return (b & 0x80) ? -v : v;
}

// async global->LDS, 16B per lane. LDS side must be wave-uniform base + lane*16.
__device__ __forceinline__ void cp16(const void* g, void* l) {
    __builtin_amdgcn_global_load_lds(
        (const __attribute__((address_space(1))) uint32_t*)g,
        (__attribute__((address_space(3))) uint32_t*)l, 16, 0, 0);
}

__device__ __forceinline__ float fast_tanh(float x) {
    x = fminf(15.f, fmaxf(-15.f, x));
    float e = __expf(2.f * x);
    return (e - 1.f) / (e + 1.f);
}

// fused prep: blocks 0..255 convert Wc+Wp fp32->bf16; blocks 256..2303 span
// gathers -> bf16 ctx/phr; blocks 2304..4351 convert Wo fp32->fp8 (x32 scale)
__global__ void k_prep(const float* __restrict__ Wc, const float* __restrict__ Wp,
                       const float* __restrict__ hidden, const int* __restrict__ begins,
                       const int* __restrict__ ends, const int* __restrict__ bids,
                       const float* __restrict__ Wo, u8* __restrict__ Wo8,
                       u16* __restrict__ Wc_b, u16* __restrict__ Wp_b,
                       u16* __restrict__ ctx, u16* __restrict__ phr) {
    int b = blockIdx.x;
    if (b >= 2304) {   // Wo fp32 -> fp8, grid-stride over 16,384,000 elems
        int i = ((b - 2304) * 256 + threadIdx.x) * 4;
        const int stride = 2048 * 256 * 4;
        for (; i < 16384000; i += stride) {
            float4 v = *(const float4*)(Wo + i);
            u8 o[4] = {f32_to_fp8(v.x * 32.f), f32_to_fp8(v.y * 32.f),
                       f32_to_fp8(v.z * 32.f), f32_to_fp8(v.w * 32.f)};
            *(uint32_t*)(Wo8 + i) = *(const uint32_t*)o;
        }
        return;
    }
    if (b < 256) {
        int i = b * 2048 + threadIdx.x * 8;
        float4 a0 = *(const float4*)(Wc + i), a1 = *(const float4*)(Wc + i + 4);
        float4 p0 = *(const float4*)(Wp + i), p1 = *(const float4*)(Wp + i + 4);
        u16 oc[8] = {f2b(a0.x), f2b(a0.y), f2b(a0.z), f2b(a0.w),
                     f2b(a1.x), f2b(a1.y), f2b(a1.z), f2b(a1.w)};
        u16 op[8] = {f2b(p0.x), f2b(p0.y), f2b(p0.z), f2b(p0.w),
                     f2b(p1.x), f2b(p1.y), f2b(p1.z), f2b(p1.w)};
        *(int4*)(Wc_b + i) = *(const int4*)oc;
        *(int4*)(Wp_b + i) = *(const int4*)op;
        return;
    }
    int l = b - 256;
    int bg = begins[l], e = ends[l], bd = bids[l];
    const float* h_bm1 = hidden + ((size_t)(bg - 1) * 32 + bd) * 1024;
    const float* h_e   = hidden + ((size_t)e * 32 + bd) * 1024;
    const float* h_b   = hidden + ((size_t)bg * 32 + bd) * 1024;
    const float* h_em1 = hidden + ((size_t)(e - 1) * 32 + bd) * 1024;
    int d = threadIdx.x * 4;
    float4 c4 = (d < 512) ? *(const float4*)(h_bm1 + d) : *(const float4*)(h_e + d);
    float4 b4 = *(const float4*)(h_b + d);
    float4 e4 = *(const float4*)(h_em1 + d);
    u16 co[4] = {f2b(c4.x), f2b(c4.y), f2b(c4.z), f2b(c4.w)};
    u16 po[4] = {f2b(0.5f * (b4.x + e4.x)), f2b(0.5f * (b4.y + e4.y)),
                 f2b(0.5f * (b4.z + e4.z)), f2b(0.5f * (b4.w + e4.w))};
    *(uint64_t*)(ctx + (size_t)l * 1024 + d) = *(const uint64_t*)co;
    *(uint64_t*)(phr + (size_t)l * 1024 + d) = *(const uint64_t*)po;
}

// feats8[z*2048+m][n] = fp8(16 * tanh(A[m].W[n] + bias[n])), bf16 MFMA inputs
__global__ __launch_bounds__(256) void k_feats(const u16* __restrict__ ctx, const u16* __restrict__ phr,
        const u16* __restrict__ Wc, const u16* __restrict__ Wp,
        const float* __restrict__ bc, const float* __restrict__ bp,
        u8* __restrict__ feats) {
    __shared__ __align__(16) u16 lA[64 * 32];
    __shared__ __align__(16) u16 lB[64 * 32];
    int z = blockIdx.z;
    const u16* A = z ? phr : ctx;
    const u16* W = z ? Wp : Wc;
    const float* bias = z ? bp : bc;
    int m0 = blockIdx.x * 64;
    int n0 = blockIdx.y * 64;
    int t = threadIdx.x;
    int lane = t & 63, w = t >> 6;
    int lrow = lane & 15, lq = lane >> 4;
    f32x4 zero = {0.f, 0.f, 0.f, 0.f};
    f32x4 acc[4];
    for (int i = 0; i < 4; i++) acc[i] = zero;
    int row = t >> 2, kseg = (t & 3) * 8;
    for (int kt = 0; kt < 32; kt++) {
        int k0 = kt * 32;
        __syncthreads();
        cp16(&A[(size_t)(m0 + row) * 1024 + k0 + kseg], &lA[t * 8]);
        cp16(&W[(size_t)(n0 + row) * 1024 + k0 + kseg], &lB[t * 8]);
        __syncthreads();
        bf16x8 af = *(bf16x8*)&lA[(w * 16 + lrow) * 32 + lq * 8];
        for (int ns = 0; ns < 4; ns++) {
            bf16x8 bfr = *(bf16x8*)&lB[(ns * 16 + lrow) * 32 + lq * 8];
            acc[ns] = __builtin_amdgcn_mfma_f32_16x16x32_bf16(af, bfr, acc[ns], 0, 0, 0);
        }
    }
    int zbase = z * 2048;
    for (int ns = 0; ns < 4; ns++) {
        int col = n0 + ns * 16 + lrow;
        float bv = bias[col];
        for (int r = 0; r < 4; r++) {
            int orow = zbase + m0 + w * 16 + lq * 4 + r;
            feats[(size_t)orow * 512 + col] = f32_to_fp8(16.f * fast_tanh(acc[ns][r] + bv));
        }
    }
}

// big GEMM + row sum-of-exp, MX-fp8: feats8[4096][512] @ Wo8[32000][512]^T.
//
// v9 = v8 shell (independent 2-wave blocks, grid (32,8,4), 4 blocks/CU,
// __launch_bounds__(128,2) -> 256-reg cap, 8 waves/CU) with v5's PROVEN-LEAN
// inner loop/epilogue restored verbatim. v8's (uintptr)pb^16 pointer trick
// inflated VALU-busy 26.8 -> 41.6us (same math, 1.55x insts): it defeated
// adjacent regalloc of the blo/bhi ds_read_b128 pair, so each i32x8 MFMA
// operand was assembled via v_mov chains. v5's plain xoA/xoB form measured
// 26.8us VALU-busy -- keep exactly that codegen shape.
// Wave = 64 rows x 32 cols (mi=4, ni=2), af[4][4] = 128 regs (AGPR half).
// 4-slot quarter ring (4x4KB LDS), depth-3 prefetch, counted vmcnt 4/2/0,
// one s_barrier per kc, setprio(1) around MFMA, 16B-slot XOR swizzle.
// No max-tracking: |logit| <= 22.6, exp never overflows fp32.
__global__ __launch_bounds__(128, 2) void k_lse(const u8* __restrict__ feats,
        const u8* __restrict__ Wo, const float* __restrict__ bo, float* __restrict__ ps) {
    __shared__ __align__(16) u8 lds[4][32 * 128];    // quarter B ring = 16 KB
    int m0 = blockIdx.x * 128;
    int sc = blockIdx.y;
    int q  = blockIdx.z;                             // col-quarter 0..3
    int ts = (NTILES * sc) / NSC, te = (NTILES * (sc + 1)) / NSC;
    int t = threadIdx.x;                             // 0..127
    int lane = t & 63, w = t >> 6;                   // w = 0..1: row-half
    int lrow = lane & 15, lq = lane >> 4;
    int wrow = w * 64;
    int xm = lrow & 7;                 // swizzle key (row&7 == lrow&7 for our rows)
    int xoA = ((2 * lq) ^ xm) * 16;    // swizzled 16B slots for source k-chunks 2lq, 2lq+1
    int xoB = ((2 * lq + 1) ^ xm) * 16;

    // staging: 256 16B chunks per slot (32 rows x 8 slots), 2 per thread
    // (c = t and c = t+128; +128 -> row+16, same slot/XOR since 16%8==0).
    // chunk c -> row c>>3, phys slot c&7; src k-chunk = (c&7)^((c>>3)&7).
    int srow = t >> 3;
    int kb = ((t & 7) ^ ((t >> 3) & 7)) * 16;

    auto stageB = [&](int slot, int gr) {
        const u8* pB = Wo + (size_t)((gr >> 2) * 128 + q * 32 + srow) * 512
                     + (gr & 3) * 128 + kb;
        cp16(pB, &lds[slot][t * 16]);
        cp16(pB + (size_t)16 * 512, &lds[slot][t * 16 + 2048]);
    };

    int gr0 = ts * 4;                  // gr0 % 4 == 0 -> slot = gr & 3
    stageB(0, gr0);
    stageB(1, gr0 + 1);
    stageB(2, gr0 + 2);

    // ---- A tile -> registers (once per block); rows m0+wrow+mi*16+lrow ----
    i32x8 af[4][4];
#pragma unroll
    for (int mi = 0; mi < 4; mi++) {
        const u8* pa = feats + (size_t)(m0 + wrow + mi * 16 + lrow) * 512 + lq * 32;
#pragma unroll
        for (int kc = 0; kc < 4; kc++) {
            i32x4 lo = *(const i32x4*)(pa + kc * 128);
            i32x4 hi = *(const i32x4*)(pa + kc * 128 + 16);
            af[mi][kc] = __builtin_shufflevector(lo, hi, 0, 1, 2, 3, 4, 5, 6, 7);
        }
    }

    float s_state[4][4];
    for (int mi = 0; mi < 4; mi++)
        for (int r = 0; r < 4; r++) s_state[mi][r] = 0.f;
    f32x4 zero = {0.f, 0.f, 0.f, 0.f};
    f32x4 acc[4][2];
    const float inv512 = 1.f / 512.f;

    for (int tile = ts; tile < te; ++tile) {
        int grt = tile * 4;
        bool notlast = (tile + 1 < te);
#pragma unroll
        for (int mi = 0; mi < 4; mi++)
#pragma unroll
            for (int ni = 0; ni < 2; ni++) acc[mi][ni] = zero;
#pragma unroll
        for (int kc = 0; kc < 4; kc++) {
            // slot kc ready once all but the 2 newer stages (2 cp16 each) retired
            if (notlast || kc < 2)
                asm volatile("s_waitcnt vmcnt(4)" ::: "memory");
            else if (kc == 2)
                asm volatile("s_waitcnt vmcnt(2)" ::: "memory");
            else
                asm volatile("s_waitcnt vmcnt(0)" ::: "memory");
            __builtin_amdgcn_s_barrier();
            if (notlast || kc == 0)
                stageB((kc + 3) & 3, grt + kc + 3);   // prefetch depth 3
            const u8* bufB = lds[kc];
            __builtin_amdgcn_s_setprio(1);
#pragma unroll
            for (int ni = 0; ni < 2; ni++) {
                const u8* pb = bufB + (ni * 16 + lrow) * 128;
                i32x4 blo = *(const i32x4*)(pb + xoA);
                i32x4 bhi = *(const i32x4*)(pb + xoB);
                i32x8 bfr = __builtin_shufflevector(blo, bhi, 0, 1, 2, 3, 4, 5, 6, 7);
#pragma unroll
                for (int mi = 0; mi < 4; mi++)
                    acc[mi][ni] = __builtin_amdgcn_mfma_scale_f32_16x16x128_f8f6f4(
                        af[mi][kc], bfr, acc[mi][ni], 0, 0,
                        0, 0x7F7F7F7F, 0, 0x7F7F7F7F);
            }
            __builtin_amdgcn_s_setprio(0);
        }
        // epilogue for this n-tile: exp accumulate (overlaps in-flight stages)
        int n0 = tile * 128 + q * 32;
#pragma unroll
        for (int ni = 0; ni < 2; ni++) {
            float bv = bo[n0 + ni * 16 + lrow];
#pragma unroll
            for (int mi = 0; mi < 4; mi++)
#pragma unroll
                for (int r = 0; r < 4; r++)
                    s_state[mi][r] += __expf(fmaf(acc[mi][ni][r], inv512, bv));
        }
    }
    // merge cols across the 16 lanes of each quad-group (xor 1,2,4,8 stays in-group)
    for (int mi = 0; mi < 4; mi++)
    for (int r = 0; r < 4; r++) {
        float s = s_state[mi][r];
        for (int off = 1; off < 16; off <<= 1) s += __shfl_xor(s, off);
        if (lrow == 0) {
            int row = m0 + wrow + mi * 16 + lq * 4 + r;
            ps[row * NPART + sc * 4 + q] = s;
        }
    }
}

// tag logits from fp8: one wave per row does BOTH tags; logit = dot/512 + bo
__global__ void k_taglog(const u8* __restrict__ feats, const u8* __restrict__ Wo,
        const float* __restrict__ bo, const int* __restrict__ tags, float* __restrict__ tlog) {
    int i = blockIdx.x * 4 + (threadIdx.x >> 6);   // row 0..4095
    int lane = threadIdx.x & 63;
    int t0 = tags[(i & 2047) * 2 + 0];
    int t1 = tags[(i & 2047) * 2 + 1];
    uint64_t fa = *(const uint64_t*)(feats + (size_t)i * 512 + lane * 8);
    uint64_t wa = *(const uint64_t*)(Wo + (size_t)t0 * 512 + lane * 8);
    uint64_t wb = *(const uint64_t*)(Wo + (size_t)t1 * 512 + lane * 8);
    float s0 = 0.f, s1 = 0.f;
    for (int j = 0; j < 8; j++) {
        float fv = fp8_val((int)((fa >> (8 * j)) & 0xFF));
        s0 += fv * fp8_val((int)((wa >> (8 * j)) & 0xFF));
        s1 += fv * fp8_val((int)((wb >> (8 * j)) & 0xFF));
    }
    for (int off = 32; off >= 1; off >>= 1) {
        s0 += __shfl_down(s0, off);
        s1 += __shfl_down(s1, off);
    }
    if (lane == 0) {
        tlog[i * 2 + 0] = s0 * (1.f / 512.f) + bo[t0];
        tlog[i * 2 + 1] = s1 * (1.f / 512.f) + bo[t1];
    }
}

// lse = log(sum of chunk partials) + loss; 16 blocks x 256 rows, atomicAdd
__global__ void k_final(const float* __restrict__ ps,
        const float* __restrict__ tlog, const int* __restrict__ tags,
        const float* __restrict__ dp, float* __restrict__ out) {
    __shared__ float red[256];
    int i = blockIdx.x * 256 + threadIdx.x;
    float S = 0.f;
    for (int j = 0; j < NPART; j++) S += ps[i * NPART + j];
    float lse = logf(S);
    float num = 0.f, den = 0.f;
    for (int k = 0; k < 2; k++) {
        int tg = tags[(i & 2047) * 2 + k];
        float r = 1.0f - dp[tg];
        num += r * (lse - tlog[i * 2 + k]);
        den += r;
    }
    red[threadIdx.x] = num / den;
    __syncthreads();
    for (int s = 128; s > 0; s >>= 1) {
        if (threadIdx.x < s) red[threadIdx.x] += red[threadIdx.x + s];
        __syncthreads();
    }
    if (threadIdx.x == 0) atomicAdd(out, red[0] / (4096.0f + 1e-5f));
}

extern "C" void kernel_launch(void* const* d_in, const int* in_sizes, int n_in,
                              void* d_out, int out_size, void* d_ws, size_t ws_size,
                              hipStream_t stream) {
    const float* hidden = (const float*)d_in[0];
    const float* Wc     = (const float*)d_in[1];
    const float* bc     = (const float*)d_in[2];
    const float* Wp     = (const float*)d_in[3];
    const float* bp     = (const float*)d_in[4];
    const float* Wo     = (const float*)d_in[5];
    const float* bo     = (const float*)d_in[6];
    const float* dp     = (const float*)d_in[7];
    const int* begins   = (const int*)d_in[8];
    const int* ends     = (const int*)d_in[9];
    const int* bids     = (const int*)d_in[10];
    const int* tags     = (const int*)d_in[11];
    float* out = (float*)d_out;

    // workspace carve (all 16B-aligned)
    u8*  Wo8     = (u8*)d_ws;                          // 16,384,000 B (fp8 x32)
    u16* Wc_b    = (u16*)((char*)d_ws + 16384000);     // 512*1024 bf16
    u16* Wp_b    = Wc_b + 524288;
    u16* ctx_b   = Wp_b + 524288;                      // 2048*1024 bf16
    u16* phr_b   = ctx_b + 2097152;
    u8*  feats8  = (u8*)(phr_b + 2097152);             // 4096*512 fp8 x16
    // ps/tlog alias the ctx region (dead after k_feats; in-stream order safe)
    float* ps    = (float*)ctx_b;                      // 4096*32*4 = 512 KB
    float* tlog  = ps + NROWS * NPART;                 // 8192

    k_prep<<<4352, 256, 0, stream>>>(Wc, Wp, hidden, begins, ends, bids,
                                     Wo, Wo8, Wc_b, Wp_b, ctx_b, phr_b);
    k_feats<<<dim3(32, 8, 2), 256, 0, stream>>>(ctx_b, phr_b, Wc_b, Wp_b, bc, bp, feats8);
    k_lse<<<dim3(32, NSC, 4), 128, 0, stream>>>(feats8, Wo8, bo, ps);
    k_taglog<<<1024, 256, 0, stream>>>(feats8, Wo8, bo, tags, tlog);
    hipMemsetAsync(d_out, 0, sizeof(float), stream);
    k_final<<<16, 256, 0, stream>>>(ps, tlog, tags, dp, out);
}